// Round 3
// baseline (75.729 us; speedup 1.0000x reference)
//
#include <hip/hip_runtime.h>
#include <math.h>

namespace {
constexpr int N_ = 2, C_ = 64, HR_ = 60, WR_ = 80, HW_ = HR_ * WR_; // 4800
constexpr int K_ = 1024, GS_ = 8, H_ = HR_ * GS_, W_ = WR_ * GS_;  // 480, 640
constexpr int KT_ = 16;
constexpr int CH_ = (HW_ + 255) / 256;                             // 19 chunks of 256
constexpr float NEGBIG = -3.0e38f, POSBIG = 3.0e38f;
}

// Kernel A: bilinear sample desc1 at keypoints; one thread per (k, c).
// Also emits ||kp1_desc[k]||^2 (wave reduction; one wave == one keypoint)
// and the kp_grid coords with the reference's .at[:,0]/.at[:,1] quirk
// (only keypoints 0 and 1 are divided by GS).
__global__ __launch_bounds__(256) void k_sample(
    const float* __restrict__ kp1, const float* __restrict__ desc1,
    float* __restrict__ out_desc, float* __restrict__ kpd,
    float* __restrict__ ksq, float* __restrict__ kpgx, float* __restrict__ kpgy)
{
  int t = blockIdx.x * 256 + threadIdx.x;
  int k = t >> 6, c = t & 63;
  float bf = kp1[k * 4 + 0];
  float yr = kp1[k * 4 + 2];
  float xr = kp1[k * 4 + 3];
  int b = (int)bf;
  float x = fminf(fmaxf(xr * (1.0f / GS_), 0.0f), (float)(WR_ - 1));
  float y = fminf(fmaxf(yr * (1.0f / GS_), 0.0f), (float)(HR_ - 1));
  float x0f = floorf(x), y0f = floorf(y);
  float x1f = fminf(x0f + 1.0f, (float)(WR_ - 1));
  float y1f = fminf(y0f + 1.0f, (float)(HR_ - 1));
  float wx = x - x0f, wy = y - y0f;
  int x0 = (int)x0f, x1 = (int)x1f, y0 = (int)y0f, y1 = (int)y1f;
  const float* dbase = desc1 + ((size_t)b * C_ + c) * HW_;
  float v00 = dbase[y0 * WR_ + x0], v01 = dbase[y0 * WR_ + x1];
  float v10 = dbase[y1 * WR_ + x0], v11 = dbase[y1 * WR_ + x1];
  float v = (1.0f - wy) * ((1.0f - wx) * v00 + wx * v01)
          + wy * ((1.0f - wx) * v10 + wx * v11);
  out_desc[k * C_ + c] = v;
  kpd[k * C_ + c] = v;
  float sq = v * v;
  #pragma unroll
  for (int m = 1; m < 64; m <<= 1) sq += __shfl_xor(sq, m);
  if (c == 0) {
    ksq[k] = sq;
    // Reference quirk: kp_grid.at[:,0] / .at[:,1] index the KEYPOINT axis,
    // so only keypoints 0 and 1 get divided by GS.
    kpgx[k] = (k < 2) ? xr * (1.0f / GS_) : xr;
    kpgy[k] = (k < 2) ? yr * (1.0f / GS_) : yr;
  }
}

// Kernel B: per (n, hw): warped grid coords, visibility product over 8x8 cell,
// and ||desc2[n,:,hw]||^2.
__global__ __launch_bounds__(256) void k_prep(
    const float* __restrict__ desc2, const float* __restrict__ homo,
    const float* __restrict__ vis,
    float* __restrict__ wxa, float* __restrict__ wya,
    float* __restrict__ vma, float* __restrict__ dsa)
{
  int t = blockIdx.x * 256 + threadIdx.x;
  if (t >= N_ * HW_) return;
  int n = t / HW_, hw = t % HW_;
  int h = hw / WR_, w = hw % WR_;
  float gx = (float)(w * GS_ + GS_ / 2);
  float gy = (float)(h * GS_ + GS_ / 2);
  const float* hm = homo + n * 9;
  float w0 = fmaf(hm[0], gx, fmaf(hm[1], gy, hm[2]));
  float w1 = fmaf(hm[3], gx, fmaf(hm[4], gy, hm[5]));
  float w2 = fmaf(hm[6], gx, fmaf(hm[7], gy, hm[8]));
  wxa[t] = w0 / w2;
  wya[t] = w1 / w2;
  const float* vb = vis + (size_t)n * H_ * W_ + (size_t)(h * GS_) * W_ + w * GS_;
  float p = 1.0f;
  #pragma unroll
  for (int i = 0; i < GS_; i++)
    #pragma unroll
    for (int j = 0; j < GS_; j++) p *= vb[i * W_ + j];
  vma[t] = p;
  const float* d2 = desc2 + (size_t)n * C_ * HW_ + hw;
  float s = 0.0f;
  #pragma unroll
  for (int c = 0; c < C_; c++) { float dv = d2[c * HW_]; s = fmaf(dv, dv, s); }
  dsa[t] = s;
}

// Kernel C: main reduction. Block = (n, tile of 16 keypoints, one 256-wide hw
// chunk). Each thread holds one desc2 column (64 floats) in registers.
// Keypoint descriptors are read through WAVE-UNIFORM addresses -> s_load +
// v_fmac with SGPR operand. 2432 blocks -> ~8 waves/SIMD to hide s_load
// latency; only the last chunk per (n,kt) has idle lanes (192/256).
__global__ __launch_bounds__(256) void k_main(
    const float* __restrict__ desc2,
    const float* __restrict__ kpd, const float* __restrict__ kpgx,
    const float* __restrict__ kpgy, const float* __restrict__ ksq,
    const float* __restrict__ wxa, const float* __restrict__ wya,
    const float* __restrict__ vma, const float* __restrict__ dsa,
    float* __restrict__ accP, float* __restrict__ accN)
{
  __shared__ float redP[4][KT_], redN[4][KT_];
  int tid = threadIdx.x;
  int bx = blockIdx.x;
  int n = bx / ((K_ / KT_) * CH_);
  int rem = bx % ((K_ / KT_) * CH_);
  int kt = rem / CH_, ch = rem % CH_;
  int k0 = kt * KT_;

  float mP[KT_], mN[KT_];
  #pragma unroll
  for (int k = 0; k < KT_; k++) { mP[k] = NEGBIG; mN[k] = POSBIG; }

  const float* dbase = desc2 + (size_t)n * C_ * HW_;
  int off = ch * 256 + tid;
  bool valid = off < HW_;
  int hw = valid ? off : 0;

  float dcol[C_];
  #pragma unroll
  for (int c = 0; c < C_; c++) dcol[c] = dbase[c * HW_ + hw];
  float wxv = wxa[n * HW_ + hw], wyv = wya[n * HW_ + hw];
  float dsv = dsa[n * HW_ + hw];
  float vm5 = (vma[n * HW_ + hw] != 0.0f) ? 5.0f : 0.0f;

  #pragma unroll
  for (int k = 0; k < KT_; k++) {
    const float* kb = kpd + (k0 + k) * C_;  // wave-uniform -> s_load
    float s0 = 0.f, s1 = 0.f, s2 = 0.f, s3 = 0.f;
    #pragma unroll
    for (int q = 0; q < 16; q++) {
      s0 = fmaf(kb[4 * q + 0], dcol[4 * q + 0], s0);
      s1 = fmaf(kb[4 * q + 1], dcol[4 * q + 1], s1);
      s2 = fmaf(kb[4 * q + 2], dcol[4 * q + 2], s2);
      s3 = fmaf(kb[4 * q + 3], dcol[4 * q + 3], s3);
    }
    float dot = (s0 + s1) + (s2 + s3);
    float d2v = fmaxf(ksq[k0 + k] + dsv - 2.0f * dot, 1e-12f);
    float dist = sqrtf(d2v);
    float dx = kpgx[k0 + k] - wxv, dy = kpgy[k0 + k] - wyv;
    bool inside = fmaf(dx, dx, dy * dy) <= 56.25f;  // (GS-0.5)^2
    float posv = dist - (inside ? 0.0f : vm5);
    float negv = dist + (inside ? vm5 : 0.0f);
    if (valid) { mP[k] = fmaxf(mP[k], posv); mN[k] = fminf(mN[k], negv); }
  }

  // wave butterfly reduction (64 lanes)
  #pragma unroll
  for (int k = 0; k < KT_; k++) {
    #pragma unroll
    for (int m = 1; m < 64; m <<= 1) {
      mP[k] = fmaxf(mP[k], __shfl_xor(mP[k], m));
      mN[k] = fminf(mN[k], __shfl_xor(mN[k], m));
    }
  }
  int wave = tid >> 6, lane = tid & 63;
  if (lane == 0) {
    #pragma unroll
    for (int k = 0; k < KT_; k++) { redP[wave][k] = mP[k]; redN[wave][k] = mN[k]; }
  }
  __syncthreads();
  if (tid < KT_) {
    int k = tid;
    float p = fmaxf(fmaxf(redP[0][k], redP[1][k]), fmaxf(redP[2][k], redP[3][k]));
    float q = fminf(fminf(redN[0][k], redN[1][k]), fminf(redN[2][k], redN[3][k]));
    int slot = (n * K_ + k0 + k) * CH_ + ch;
    accP[slot] = p; accN[slot] = q;
  }
}

// Kernel D: combine hw-chunks, triplet margin, deterministic tree-sum, mean.
__global__ __launch_bounds__(256) void k_final(
    const float* __restrict__ accP, const float* __restrict__ accN,
    float* __restrict__ out)
{
  int tid = threadIdx.x;
  float local = 0.0f;
  for (int i = tid; i < N_ * K_; i += 256) {
    float p = NEGBIG, q = POSBIG;
    #pragma unroll
    for (int cv = 0; cv < CH_; ++cv) {
      int slot = i * CH_ + cv;
      p = fmaxf(p, accP[slot]);
      q = fminf(q, accN[slot]);
    }
    local += fmaxf(p - q + 1.0f, 0.0f);
  }
  __shared__ float sh[256];
  sh[tid] = local;
  __syncthreads();
  for (int o = 128; o > 0; o >>= 1) {
    if (tid < o) sh[tid] += sh[tid + o];
    __syncthreads();
  }
  if (tid == 0) out[0] = sh[0] * (1.0f / (N_ * K_));
}

extern "C" void kernel_launch(void* const* d_in, const int* in_sizes, int n_in,
                              void* d_out, int out_size, void* d_ws, size_t ws_size,
                              hipStream_t stream) {
  const float* kp1   = (const float*)d_in[0];
  const float* desc1 = (const float*)d_in[1];
  const float* desc2 = (const float*)d_in[2];
  const float* homo  = (const float*)d_in[3];
  const float* vis   = (const float*)d_in[4];
  float* out = (float*)d_out;

  float* ws = (float*)d_ws;
  float* kpgx = ws;                  // K
  float* kpgy = kpgx + K_;           // K
  float* ksq  = kpgy + K_;           // K
  float* kpd  = ksq + K_;            // K*C
  float* wxa  = kpd + K_ * C_;       // N*HW
  float* wya  = wxa + N_ * HW_;      // N*HW
  float* vma  = wya + N_ * HW_;      // N*HW
  float* dsa  = vma + N_ * HW_;      // N*HW
  float* accP = dsa + N_ * HW_;      // N*K*CH
  float* accN = accP + N_ * K_ * CH_;

  hipLaunchKernelGGL(k_sample, dim3(K_ * C_ / 256), dim3(256), 0, stream,
                     kp1, desc1, out + 1, kpd, ksq, kpgx, kpgy);
  hipLaunchKernelGGL(k_prep, dim3((N_ * HW_ + 255) / 256), dim3(256), 0, stream,
                     desc2, homo, vis, wxa, wya, vma, dsa);
  hipLaunchKernelGGL(k_main, dim3(N_ * (K_ / KT_) * CH_), dim3(256), 0, stream,
                     desc2, kpd, kpgx, kpgy, ksq, wxa, wya, vma, dsa, accP, accN);
  hipLaunchKernelGGL(k_final, dim3(1), dim3(256), 0, stream,
                     accP, accN, out);
}

// Round 4
// 42.671 us; speedup vs baseline: 1.7747x; 1.7747x over previous
//
#include <hip/hip_runtime.h>
#include <math.h>

namespace {
constexpr int N_ = 2, C_ = 64, HR_ = 60, WR_ = 80, HW_ = HR_ * WR_; // 4800
constexpr int K_ = 1024, GS_ = 8, H_ = HR_ * GS_, W_ = WR_ * GS_;   // 480, 640
constexpr int NKT_ = 2;                 // 16-wide k-tiles per wave (32 kp)
constexpr int KTG_ = K_ / (16 * NKT_);  // 32 ktile-groups
constexpr int NS_ = 76;                 // hw-tile stripes (4 per block)
constexpr int SG_ = NS_ / 4;            // 19 stripe-groups
constexpr int TILES_ = HW_ / 16;        // 300 hw-tiles per batch
constexpr float NEGBIG = -3.0e38f, POSBIG = 3.0e38f;

typedef __attribute__((ext_vector_type(8))) short bf16x8;
typedef __attribute__((ext_vector_type(4))) float f32x4;

__device__ inline unsigned short bf16hi(float x) {
  unsigned u = __float_as_uint(x);
  unsigned r = u + 0x7FFFu + ((u >> 16) & 1u);   // RNE to bf16
  return (unsigned short)(r >> 16);
}
__device__ inline float bf16tof(unsigned short h) {
  return __uint_as_float(((unsigned)h) << 16);
}
}

// Kernel A: bilinear sample desc1 at keypoints; one thread per (k, c).
// Emits fp32 samples (output 1), bf16 hi/lo split of kpd (MFMA B operand),
// ||kp1_desc[k]||^2, and kp_grid coords with the reference's .at[:,0]/.at[:,1]
// quirk (only keypoints 0 and 1 are divided by GS).
__global__ __launch_bounds__(256) void k_sample(
    const float* __restrict__ kp1, const float* __restrict__ desc1,
    float* __restrict__ out_desc,
    unsigned short* __restrict__ kBhi, unsigned short* __restrict__ kBlo,
    float* __restrict__ ksq, float* __restrict__ kpgx, float* __restrict__ kpgy)
{
  int t = blockIdx.x * 256 + threadIdx.x;
  int k = t >> 6, c = t & 63;
  float bf = kp1[k * 4 + 0];
  float yr = kp1[k * 4 + 2];
  float xr = kp1[k * 4 + 3];
  int b = (int)bf;
  float x = fminf(fmaxf(xr * (1.0f / GS_), 0.0f), (float)(WR_ - 1));
  float y = fminf(fmaxf(yr * (1.0f / GS_), 0.0f), (float)(HR_ - 1));
  float x0f = floorf(x), y0f = floorf(y);
  float x1f = fminf(x0f + 1.0f, (float)(WR_ - 1));
  float y1f = fminf(y0f + 1.0f, (float)(HR_ - 1));
  float wx = x - x0f, wy = y - y0f;
  int x0 = (int)x0f, x1 = (int)x1f, y0 = (int)y0f, y1 = (int)y1f;
  const float* dbase = desc1 + ((size_t)b * C_ + c) * HW_;
  float v00 = dbase[y0 * WR_ + x0], v01 = dbase[y0 * WR_ + x1];
  float v10 = dbase[y1 * WR_ + x0], v11 = dbase[y1 * WR_ + x1];
  float v = (1.0f - wy) * ((1.0f - wx) * v00 + wx * v01)
          + wy * ((1.0f - wx) * v10 + wx * v11);
  out_desc[k * C_ + c] = v;
  unsigned short hi = bf16hi(v);
  kBhi[k * C_ + c] = hi;
  kBlo[k * C_ + c] = bf16hi(v - bf16tof(hi));
  float sq = v * v;
  #pragma unroll
  for (int m = 1; m < 64; m <<= 1) sq += __shfl_xor(sq, m);
  if (c == 0) {
    ksq[k] = sq;
    // Reference quirk: kp_grid.at[:,0] / .at[:,1] index the KEYPOINT axis,
    // so only keypoints 0 and 1 get divided by GS.
    kpgx[k] = (k < 2) ? xr * (1.0f / GS_) : xr;
    kpgy[k] = (k < 2) ? yr * (1.0f / GS_) : yr;
  }
}

// Kernel B: one WAVE per (n, hw). Lane = channel c.
// Produces: pAhi/pAlo = bf16 hi/lo of desc2 transposed to [n*HW][C] (MFMA A
// operand, 16B-aligned row chunks), meta[n*HW] = {wx, wy, ||d2col||^2, vm5}.
__global__ __launch_bounds__(256) void k_prep(
    const float* __restrict__ desc2, const float* __restrict__ homo,
    const float* __restrict__ vis,
    unsigned short* __restrict__ pAhi, unsigned short* __restrict__ pAlo,
    float4* __restrict__ meta)
{
  int tid = threadIdx.x, lane = tid & 63;
  int idx = blockIdx.x * 4 + (tid >> 6);       // n*HW + hw, exact (9600)
  int n = idx / HW_, hw = idx % HW_;
  int h = hw / WR_, w = hw % WR_;
  float v = desc2[((size_t)n * C_ + lane) * HW_ + hw];
  unsigned short hi = bf16hi(v);
  pAhi[(size_t)idx * C_ + lane] = hi;
  pAlo[(size_t)idx * C_ + lane] = bf16hi(v - bf16tof(hi));
  float s = v * v;                              // ||desc2[n,:,hw]||^2
  #pragma unroll
  for (int m = 1; m < 64; m <<= 1) s += __shfl_xor(s, m);
  const float* vb = vis + (size_t)n * H_ * W_ + (size_t)(h * GS_) * W_ + w * GS_;
  float p = vb[(lane >> 3) * W_ + (lane & 7)];  // 8x8 cell product
  #pragma unroll
  for (int m = 1; m < 64; m <<= 1) p *= __shfl_xor(p, m);
  if (lane == 0) {
    const float* hm = homo + n * 9;
    float gx = (float)(w * GS_ + GS_ / 2);
    float gy = (float)(h * GS_ + GS_ / 2);
    float w0 = fmaf(hm[0], gx, fmaf(hm[1], gy, hm[2]));
    float w1 = fmaf(hm[3], gx, fmaf(hm[4], gy, hm[5]));
    float w2 = fmaf(hm[6], gx, fmaf(hm[7], gy, hm[8]));
    meta[idx] = make_float4(w0 / w2, w1 / w2, s, (p != 0.0f) ? 5.0f : 0.0f);
  }
}

// Kernel C: MFMA main. Wave = (n, 32-kp group, hw-stripe of <=4 16-row tiles).
// S[hw][kp] via mfma_f32_16x16x32_bf16 with fp32 emulated as bf16 hi/lo split
// (hi*hi + hi*lo + lo*hi). D layout (m89): col=lane&15 (kp), row=(lane>>4)*4+reg
// (hw). hw-reduction: 4 in-reg + shfl_xor(16,32). Block = 4 stripes, LDS-combine.
__global__ __launch_bounds__(256) void k_main(
    const unsigned short* __restrict__ pAhi, const unsigned short* __restrict__ pAlo,
    const unsigned short* __restrict__ kBhi, const unsigned short* __restrict__ kBlo,
    const float* __restrict__ ksq, const float* __restrict__ kpgx,
    const float* __restrict__ kpgy, const float4* __restrict__ meta,
    float* __restrict__ accP, float* __restrict__ accN)
{
  __shared__ float redP[4][NKT_][16], redN[4][NKT_][16];
  int tid = threadIdx.x, wv = tid >> 6, lane = tid & 63;
  int bx = blockIdx.x;
  int n = bx / (KTG_ * SG_);
  int rem = bx % (KTG_ * SG_);
  int ktg = rem / SG_, sg = rem % SG_;
  int s = sg * 4 + wv;
  int k0 = ktg * (16 * NKT_);
  int l15 = lane & 15, lhi = lane >> 4;

  // Per-keypoint scalars + B fragments (resident for the whole wave)
  float kq[NKT_], kx[NKT_], ky[NKT_];
  bf16x8 bh[NKT_][2], bl[NKT_][2];
  #pragma unroll
  for (int kt = 0; kt < NKT_; kt++) {
    int kidx = k0 + kt * 16 + l15;
    kq[kt] = ksq[kidx]; kx[kt] = kpgx[kidx]; ky[kt] = kpgy[kidx];
    const unsigned short* kb = kBhi + (size_t)kidx * C_ + lhi * 8;
    const unsigned short* kl = kBlo + (size_t)kidx * C_ + lhi * 8;
    bh[kt][0] = *reinterpret_cast<const bf16x8*>(kb);
    bh[kt][1] = *reinterpret_cast<const bf16x8*>(kb + 32);
    bl[kt][0] = *reinterpret_cast<const bf16x8*>(kl);
    bl[kt][1] = *reinterpret_cast<const bf16x8*>(kl + 32);
  }
  float mP[NKT_], mN[NKT_];
  #pragma unroll
  for (int kt = 0; kt < NKT_; kt++) { mP[kt] = NEGBIG; mN[kt] = POSBIG; }

  for (int i = 0; i < 4; i++) {
    int t = s + NS_ * i;
    if (t >= TILES_) break;
    int hw0 = t * 16;
    size_t abase = ((size_t)(n * HW_ + hw0 + l15)) * C_ + lhi * 8;
    bf16x8 ah0 = *reinterpret_cast<const bf16x8*>(pAhi + abase);
    bf16x8 ah1 = *reinterpret_cast<const bf16x8*>(pAhi + abase + 32);
    bf16x8 al0 = *reinterpret_cast<const bf16x8*>(pAlo + abase);
    bf16x8 al1 = *reinterpret_cast<const bf16x8*>(pAlo + abase + 32);
    const float4* mp = meta + (n * HW_ + hw0 + lhi * 4);
    float4 mt0 = mp[0], mt1 = mp[1], mt2 = mp[2], mt3 = mp[3];
    #pragma unroll
    for (int kt = 0; kt < NKT_; kt++) {
      f32x4 acc = {0.f, 0.f, 0.f, 0.f};
      acc = __builtin_amdgcn_mfma_f32_16x16x32_bf16(ah0, bh[kt][0], acc, 0, 0, 0);
      acc = __builtin_amdgcn_mfma_f32_16x16x32_bf16(ah1, bh[kt][1], acc, 0, 0, 0);
      acc = __builtin_amdgcn_mfma_f32_16x16x32_bf16(ah0, bl[kt][0], acc, 0, 0, 0);
      acc = __builtin_amdgcn_mfma_f32_16x16x32_bf16(ah1, bl[kt][1], acc, 0, 0, 0);
      acc = __builtin_amdgcn_mfma_f32_16x16x32_bf16(al0, bh[kt][0], acc, 0, 0, 0);
      acc = __builtin_amdgcn_mfma_f32_16x16x32_bf16(al1, bh[kt][1], acc, 0, 0, 0);
      #pragma unroll
      for (int r = 0; r < 4; r++) {
        float dot = acc[r];
        float4 m = (r == 0) ? mt0 : (r == 1) ? mt1 : (r == 2) ? mt2 : mt3;
        float d2v = fmaf(-2.0f, dot, kq[kt] + m.z);
        float dist = sqrtf(fmaxf(d2v, 1e-12f));
        float dx = kx[kt] - m.x, dy = ky[kt] - m.y;
        bool inside = fmaf(dx, dx, dy * dy) <= 56.25f;  // (GS-0.5)^2
        float posv = dist - (inside ? 0.0f : m.w);
        float negv = dist + (inside ? m.w : 0.0f);
        mP[kt] = fmaxf(mP[kt], posv);
        mN[kt] = fminf(mN[kt], negv);
      }
    }
  }

  // combine the 4 row-groups (lanes kp, kp+16, kp+32, kp+48)
  #pragma unroll
  for (int kt = 0; kt < NKT_; kt++) {
    mP[kt] = fmaxf(mP[kt], __shfl_xor(mP[kt], 16));
    mP[kt] = fmaxf(mP[kt], __shfl_xor(mP[kt], 32));
    mN[kt] = fminf(mN[kt], __shfl_xor(mN[kt], 16));
    mN[kt] = fminf(mN[kt], __shfl_xor(mN[kt], 32));
  }
  if (lane < 16) {
    #pragma unroll
    for (int kt = 0; kt < NKT_; kt++) {
      redP[wv][kt][lane] = mP[kt];
      redN[wv][kt][lane] = mN[kt];
    }
  }
  __syncthreads();
  if (tid < NKT_ * 16) {
    int kt = tid >> 4, kp = tid & 15;
    float p = fmaxf(fmaxf(redP[0][kt][kp], redP[1][kt][kp]),
                    fmaxf(redP[2][kt][kp], redP[3][kt][kp]));
    float q = fminf(fminf(redN[0][kt][kp], redN[1][kt][kp]),
                    fminf(redN[2][kt][kp], redN[3][kt][kp]));
    int kidx = k0 + kt * 16 + kp;
    accP[sg * (N_ * K_) + n * K_ + kidx] = p;   // [sg][pair] for coalesced final
    accN[sg * (N_ * K_) + n * K_ + kidx] = q;
  }
}

// Kernel D: combine stripe-groups, triplet margin, deterministic tree-sum, mean.
__global__ __launch_bounds__(256) void k_final(
    const float* __restrict__ accP, const float* __restrict__ accN,
    float* __restrict__ out)
{
  int tid = threadIdx.x;
  float local = 0.0f;
  for (int i = tid; i < N_ * K_; i += 256) {
    float p = NEGBIG, q = POSBIG;
    #pragma unroll
    for (int sg = 0; sg < SG_; ++sg) {
      p = fmaxf(p, accP[sg * (N_ * K_) + i]);
      q = fminf(q, accN[sg * (N_ * K_) + i]);
    }
    local += fmaxf(p - q + 1.0f, 0.0f);
  }
  __shared__ float sh[256];
  sh[tid] = local;
  __syncthreads();
  for (int o = 128; o > 0; o >>= 1) {
    if (tid < o) sh[tid] += sh[tid + o];
    __syncthreads();
  }
  if (tid == 0) out[0] = sh[0] * (1.0f / (N_ * K_));
}

extern "C" void kernel_launch(void* const* d_in, const int* in_sizes, int n_in,
                              void* d_out, int out_size, void* d_ws, size_t ws_size,
                              hipStream_t stream) {
  const float* kp1   = (const float*)d_in[0];
  const float* desc1 = (const float*)d_in[1];
  const float* desc2 = (const float*)d_in[2];
  const float* homo  = (const float*)d_in[3];
  const float* vis   = (const float*)d_in[4];
  float* out = (float*)d_out;

  // Workspace layout (16B-aligned sections): ~3.2 MB total
  float4* meta = (float4*)d_ws;                              // N*HW float4
  unsigned short* pAhi = (unsigned short*)(meta + N_ * HW_); // N*HW*C
  unsigned short* pAlo = pAhi + (size_t)N_ * HW_ * C_;
  unsigned short* kBhi = pAlo + (size_t)N_ * HW_ * C_;       // K*C
  unsigned short* kBlo = kBhi + (size_t)K_ * C_;
  float* ksq  = (float*)(kBlo + (size_t)K_ * C_);            // K
  float* kpgx = ksq + K_;
  float* kpgy = kpgx + K_;
  float* accP = kpgy + K_;                                   // SG*N*K
  float* accN = accP + SG_ * N_ * K_;

  hipLaunchKernelGGL(k_sample, dim3(K_ * C_ / 256), dim3(256), 0, stream,
                     kp1, desc1, out + 1, kBhi, kBlo, ksq, kpgx, kpgy);
  hipLaunchKernelGGL(k_prep, dim3(N_ * HW_ / 4), dim3(256), 0, stream,
                     desc2, homo, vis, pAhi, pAlo, meta);
  hipLaunchKernelGGL(k_main, dim3(N_ * KTG_ * SG_), dim3(256), 0, stream,
                     pAhi, pAlo, kBhi, kBlo, ksq, kpgx, kpgy, meta, accP, accN);
  hipLaunchKernelGGL(k_final, dim3(1), dim3(256), 0, stream,
                     accP, accN, out);
}